// Round 13
// baseline (979.131 us; speedup 1.0000x reference)
//
#include <hip/hip_runtime.h>
#include <hip/hip_bf16.h>
#include <math.h>

#define NPTS 4096
#define CO   256
#define CI   128
#define BB   4
#define DQ   64
#define LL   4
#define PST  136   // Ps row stride in shorts (272B; 16B-aligned rows)

typedef __attribute__((ext_vector_type(8))) short bf16x8;
typedef __attribute__((ext_vector_type(4))) float f32x4;

#define MFMA16(a,b,c) __builtin_amdgcn_mfma_f32_16x16x32_bf16((a),(b),(c),0,0,0)

__device__ __forceinline__ short fb(float x) {
  __hip_bfloat16 h = __float2bfloat16(x);
  return __builtin_bit_cast(short, h);
}
__device__ __forceinline__ float bf(short s) {
  unsigned u = ((unsigned)(unsigned short)s) << 16;
  return __builtin_bit_cast(float, u);
}

// ---------------------------------------------------------------------------
// one-shot fp32 -> bf16 convert of all 5 weight tensors
__global__ __launch_bounds__(256) void cvt5_k(
    const float* __restrict__ s1, short* __restrict__ d1, int n1,
    const float* __restrict__ s2, short* __restrict__ d2, int n2,
    const float* __restrict__ s3, short* __restrict__ d3, int n3,
    const float* __restrict__ s4, short* __restrict__ d4, int n4,
    const float* __restrict__ s5, short* __restrict__ d5, int n5)
{
  int i = blockIdx.x * 256 + threadIdx.x;
  const float* S; short* D;
  if      (i < n1)                       { S = s1; D = d1; }
  else if ((i -= n1) < n2)               { S = s2; D = d2; }
  else if ((i -= n2) < n3)               { S = s3; D = d3; }
  else if ((i -= n3) < n4)               { S = s4; D = d4; }
  else if ((i -= n4) < n5)               { S = s5; D = d5; }
  else return;
  const float4 a = ((const float4*)S)[i * 2];
  const float4 b = ((const float4*)S)[i * 2 + 1];
  bf16x8 r;
  r[0] = fb(a.x); r[1] = fb(a.y); r[2] = fb(a.z); r[3] = fb(a.w);
  r[4] = fb(b.x); r[5] = fb(b.y); r[6] = fb(b.z); r[7] = fb(b.w);
  ((bf16x8*)D)[i] = r;
}

// ---------------------------------------------------------------------------
// fp32 [b][C][N] -> bf16 [b][N][C] transpose-convert (stem input only)
__global__ __launch_bounds__(256) void tcvt_k(
    const float* __restrict__ X, long xbs, int C, short* __restrict__ XT)
{
  const int n0 = blockIdx.x * 64, c0 = blockIdx.y * 64, b = blockIdx.z;
  const int t = threadIdx.x, tl = t & 63, tg = t >> 6;
  __shared__ float xs[64][65];
#pragma unroll
  for (int r = 0; r < 16; ++r) {
    const int cc = tg * 16 + r;
    xs[cc][tl] = X[(long)b * xbs + (long)(c0 + cc) * NPTS + n0 + tl];
  }
  __syncthreads();
#pragma unroll
  for (int r = 0; r < 16; ++r) {
    const int nn = tg * 16 + r;
    XT[((long)b * NPTS + n0 + nn) * C + c0 + tl] = fb(xs[tl][nn]);
  }
}

// ---------------------------------------------------------------------------
// conv_a: Y[b][d][n] = sum_c Wb[d][c] * XT[b][n][c] (+bias), bf16 weights.
// OMODE 2: bf16 [d][N] + per-(channel, b, n-block) BN partial stats
template<int OMODE, bool BIAS>
__global__ __launch_bounds__(256) void conv_a(
    const short* __restrict__ XT, int C,
    const short* __restrict__ Wb, const float* __restrict__ bias,
    short* __restrict__ Yv, long ybs,
    float* __restrict__ ps1, float* __restrict__ ps2)
{
  const int n0 = blockIdx.x * 64, d0 = blockIdx.y * 64, b = blockIdx.z;
  const int tid = threadIdx.x, w = tid >> 6, l = tid & 63, lg = l >> 4, lr = l & 15;
  const short* xb = XT + (long)b * NPTS * C;
  f32x4 acc[4];
#pragma unroll
  for (int i = 0; i < 4; ++i) acc[i] = (f32x4){0.f, 0.f, 0.f, 0.f};
  const int dr = d0 + w * 16 + lr;
  for (int kc = 0; kc < C; kc += 32) {
    const bf16x8 af = *(const bf16x8*)&Wb[(long)dr * C + kc + lg * 8];
#pragma unroll
    for (int ni = 0; ni < 4; ++ni) {
      const bf16x8 bx = *(const bf16x8*)&xb[(long)(n0 + ni * 16 + lr) * C + kc + lg * 8];
      acc[ni] = MFMA16(af, bx, acc[ni]);
    }
  }
  float bv[4] = {0.f, 0.f, 0.f, 0.f};
  if (BIAS) {
    const float4 b4 = *(const float4*)&bias[d0 + w * 16 + lg * 4];
    bv[0] = b4.x; bv[1] = b4.y; bv[2] = b4.z; bv[3] = b4.w;
  }
  const int db = d0 + w * 16 + lg * 4;
  float s1[4], s2[4];
#pragma unroll
  for (int j = 0; j < 4; ++j) { s1[j] = 0.f; s2[j] = 0.f; }
#pragma unroll
  for (int ni = 0; ni < 4; ++ni) {
    const int n = n0 + ni * 16 + lr;
#pragma unroll
    for (int j = 0; j < 4; ++j) {
      const short ob = fb(acc[ni][j] + bv[j]);
      if constexpr (OMODE == 1) {
        Yv[(long)b * ybs + ((long)(n >> 7) * CO + db + j) * 128 + (n & 127)] = ob;
      } else {
        Yv[(long)b * ybs + (long)(db + j) * NPTS + n] = ob;
        const float o = bf(ob);   // stats on rounded value (self-consistent BN)
        s1[j] += o; s2[j] += o * o;
      }
    }
  }
  if constexpr (OMODE == 2) {
#pragma unroll
    for (int j = 0; j < 4; ++j) {
#pragma unroll
      for (int off = 1; off < 16; off <<= 1) {
        s1[j] += __shfl_xor(s1[j], off);
        s2[j] += __shfl_xor(s2[j], off);
      }
    }
    if (lr == 0) {
      const int slot = b * 64 + blockIdx.x;   // 256 slots per channel
#pragma unroll
      for (int j = 0; j < 4; ++j) {
        ps1[(long)(db + j) * 256 + slot] = s1[j];
        ps2[(long)(db + j) * 256 + slot] = s2[j];
      }
    }
  }
}

// ---------------------------------------------------------------------------
// conv_kv: fused K-projection (with row norms) + V-projection.
// blocks [0, 256): K role — KT[b][n][d] = XT@Wk^T, nrm2[b][n] = ||K_n||^2
// blocks [256, 1280): V role — Vblk n-blocked [n>>7][d][128] = XT@Wv^T + vb
__global__ __launch_bounds__(256) void conv_kv(
    const short* __restrict__ XT,
    const short* __restrict__ Wk, short* __restrict__ KTo, float* __restrict__ nrm2,
    const short* __restrict__ Wv, const float* __restrict__ vbias,
    short* __restrict__ Vblk)
{
  const int tid = threadIdx.x, w = tid >> 6, l = tid & 63, lg = l >> 4, lr = l & 15;
  const int bid = blockIdx.x;
  if (bid < BB * 64) {
    // ---- K role ----
    const int n0 = (bid & 63) * 64, b = bid >> 6;
    const short* xb = XT + (long)b * NPTS * CO;
    f32x4 acc[4];
#pragma unroll
    for (int i = 0; i < 4; ++i) acc[i] = (f32x4){0.f, 0.f, 0.f, 0.f};
    const long nr = n0 + w * 16 + lr;
    for (int kc = 0; kc < CO; kc += 32) {
      const bf16x8 af = *(const bf16x8*)&xb[nr * CO + kc + lg * 8];
#pragma unroll
      for (int di = 0; di < 4; ++di) {
        const bf16x8 wf = *(const bf16x8*)&Wk[(long)(di * 16 + lr) * CO + kc + lg * 8];
        acc[di] = MFMA16(af, wf, acc[di]);
      }
    }
    short* Ko = KTo + (long)b * NPTS * DQ;
    const int nb = n0 + w * 16 + lg * 4;
    float nv[4];
#pragma unroll
    for (int j = 0; j < 4; ++j) {
      nv[j] = 0.f;
#pragma unroll
      for (int di = 0; di < 4; ++di) {
        Ko[(long)(nb + j) * DQ + di * 16 + lr] = fb(acc[di][j]);
        nv[j] = fmaf(acc[di][j], acc[di][j], nv[j]);
      }
    }
#pragma unroll
    for (int j = 0; j < 4; ++j) {
#pragma unroll
      for (int off = 1; off < 16; off <<= 1) nv[j] += __shfl_xor(nv[j], off);
    }
    if (lr == 0) {
#pragma unroll
      for (int j = 0; j < 4; ++j) nrm2[(long)b * NPTS + nb + j] = nv[j];
    }
  } else {
    // ---- V role ----
    const int id = bid - BB * 64;
    const int n0 = (id & 63) * 64, d0 = ((id >> 6) & 3) * 64, b = id >> 8;
    const short* xb = XT + (long)b * NPTS * CO;
    f32x4 acc[4];
#pragma unroll
    for (int i = 0; i < 4; ++i) acc[i] = (f32x4){0.f, 0.f, 0.f, 0.f};
    const int dr = d0 + w * 16 + lr;
    for (int kc = 0; kc < CO; kc += 32) {
      const bf16x8 af = *(const bf16x8*)&Wv[(long)dr * CO + kc + lg * 8];
#pragma unroll
      for (int ni = 0; ni < 4; ++ni) {
        const bf16x8 bx = *(const bf16x8*)&xb[(long)(n0 + ni * 16 + lr) * CO + kc + lg * 8];
        acc[ni] = MFMA16(af, bx, acc[ni]);
      }
    }
    const float4 b4 = *(const float4*)&vbias[d0 + w * 16 + lg * 4];
    const float bv[4] = {b4.x, b4.y, b4.z, b4.w};
    const int db = d0 + w * 16 + lg * 4;
#pragma unroll
    for (int ni = 0; ni < 4; ++ni) {
      const int n = n0 + ni * 16 + lr;
#pragma unroll
      for (int j = 0; j < 4; ++j)
        Vblk[(long)b * CO * NPTS + ((long)(n >> 7) * CO + db + j) * 128 + (n & 127)] =
            fb(acc[ni][j] + bv[j]);
    }
  }
}

// ---------------------------------------------------------------------------
// BN normalize + affine + ReLU on bf16 pre-BN tensor [b][c][N], with the
// channel-stat finalize FUSED as a prologue (reads the 256 partials for the
// block's 64 channels; deterministic per-block reduction order).
// Optionally write fp32 [c][n] (final out) and/or bf16 transpose [n][CO].
template<bool WF32, bool WBF>
__global__ __launch_bounds__(256) void bnrelu_t(
    const short* __restrict__ X, long xbs,
    const float* __restrict__ ps1, const float* __restrict__ ps2,
    const float* __restrict__ g, const float* __restrict__ be,
    float* __restrict__ Yf, long ybs, short* __restrict__ XT)
{
  const int n0 = blockIdx.x * 64, c0 = blockIdx.y * 64, b = blockIdx.z;
  const int t = threadIdx.x, tl = t & 63, tg = t >> 6;
  __shared__ float xs[64][65];
  __shared__ float red1[4][64], red2[4][64];
  __shared__ float msh[64], ash[64], bsh[64];

  // ---- fused BN finalize: stats for channels c0..c0+63 ----
  {
    float s = 0.f, s2 = 0.f;
    const float* p1 = ps1 + (long)(c0 + tl) * 256 + tg * 64;
    const float* p2 = ps2 + (long)(c0 + tl) * 256 + tg * 64;
#pragma unroll 8
    for (int i = 0; i < 64; ++i) { s += p1[i]; s2 += p2[i]; }
    red1[tg][tl] = s; red2[tg][tl] = s2;
  }
  __syncthreads();
  if (t < 64) {
    const float S  = (red1[0][t] + red1[1][t]) + (red1[2][t] + red1[3][t]);
    const float S2 = (red2[0][t] + red2[1][t]) + (red2[2][t] + red2[3][t]);
    const float m  = S / (float)(BB * NPTS);
    const float v  = S2 / (float)(BB * NPTS) - m * m;
    msh[t] = m;
    ash[t] = rsqrtf(v + 1e-5f) * g[c0 + t];   // fold gamma into scale
    bsh[t] = be[c0 + t];
  }
  __syncthreads();

  // ---- normalize + ReLU + optional transpose ----
#pragma unroll
  for (int r = 0; r < 16; ++r) {
    const int cc = tg * 16 + r, c = c0 + cc;
    float v = bf(X[(long)b * xbs + (long)c * NPTS + n0 + tl]);
    v = fmaxf(fmaf(v - msh[cc], ash[cc], bsh[cc]), 0.f);
    if (WF32) Yf[(long)b * ybs + (long)c * NPTS + n0 + tl] = v;
    xs[cc][tl] = v;
  }
  __syncthreads();
  if (WBF) {
#pragma unroll
    for (int r = 0; r < 16; ++r) {
      const int nn = tg * 16 + r;
      XT[((long)b * NPTS + n0 + nn) * CO + c0 + tl] = fb(xs[tl][nn]);
    }
  }
}

// ---------------------------------------------------------------------------
// rowsum: psum[chunk][b][n] = sum_{m in chunk} exp(S[n,m] - M_n), with the
// Cauchy-Schwarz bound computation FUSED as a prologue: each block reduces
// the batch max of nrm2 (deterministic), derives M_n = sqrt(nrm2[n]*maxnrm2)
// for its rows, and writes rmaxb (redundantly-identical across chunks) for
// pass2. XCD-swizzled flat grid.
__global__ __launch_bounds__(256) void rowsum_mfma(
    const short* __restrict__ KT, const float* __restrict__ nrm2,
    float* __restrict__ rmaxb, float* __restrict__ psum)
{
  const int bid = blockIdx.x;
  const int b = (bid >> 1) & 3;
  const int idx = (bid >> 3) * 2 + (bid & 1);   // 0..255
  const int n0 = (idx & 63) * 64;
  const int chunk = idx >> 6;
  const int tid = threadIdx.x, w = tid >> 6, l = tid & 63, lg = l >> 4, lr = l & 15;

  // ---- fused bound: batch max of nrm2 ----
  __shared__ float redm[4];
  const float* nb_ = nrm2 + (long)b * NPTS;
  float mx = 0.f;
  for (int n = tid; n < NPTS; n += 256) mx = fmaxf(mx, nb_[n]);
#pragma unroll
  for (int o = 32; o > 0; o >>= 1) mx = fmaxf(mx, __shfl_down(mx, o));
  if ((tid & 63) == 0) redm[tid >> 6] = mx;
  __syncthreads();
  const float mv = fmaxf(fmaxf(redm[0], redm[1]), fmaxf(redm[2], redm[3]));
  // write rmax for this block's 64 rows (all chunk-blocks write identical values)
  if (tid < 64) rmaxb[(long)b * NPTS + n0 + tid] = sqrtf(nb_[n0 + tid] * mv);

  const short* Kb = KT + (long)b * NPTS * DQ;
  const int nr = n0 + w * 16 + lr;
  const bf16x8 a0 = *(const bf16x8*)&Kb[(long)nr * DQ + lg * 8];
  const bf16x8 a1 = *(const bf16x8*)&Kb[(long)nr * DQ + 32 + lg * 8];
  float M4[4];
#pragma unroll
  for (int j = 0; j < 4; ++j)
    M4[j] = sqrtf(nb_[n0 + w * 16 + lg * 4 + j] * mv);

  float sm[4][4];
#pragma unroll
  for (int p = 0; p < 4; ++p)
#pragma unroll
    for (int j = 0; j < 4; ++j) sm[p][j] = 0.f;

  const int mc = chunk * (NPTS / 4);
  for (int m0 = mc; m0 < mc + NPTS / 4; m0 += 64) {
#pragma unroll
    for (int p = 0; p < 4; ++p) {
      const bf16x8 b0 = *(const bf16x8*)&Kb[(long)(m0 + p * 16 + lr) * DQ + lg * 8];
      const bf16x8 b1 = *(const bf16x8*)&Kb[(long)(m0 + p * 16 + lr) * DQ + 32 + lg * 8];
      f32x4 s = {0.f, 0.f, 0.f, 0.f};
      s = MFMA16(a0, b0, s);
      s = MFMA16(a1, b1, s);
      sm[p][0] += __expf(s[0] - M4[0]);
      sm[p][1] += __expf(s[1] - M4[1]);
      sm[p][2] += __expf(s[2] - M4[2]);
      sm[p][3] += __expf(s[3] - M4[3]);
    }
  }
  float sf[4];
#pragma unroll
  for (int j = 0; j < 4; ++j)
    sf[j] = (sm[0][j] + sm[1][j]) + (sm[2][j] + sm[3][j]);
#pragma unroll
  for (int off = 1; off < 16; off <<= 1)
#pragma unroll
    for (int j = 0; j < 4; ++j) sf[j] += __shfl_xor(sf[j], off);

  if (lr == 0) {
    const long base = ((long)chunk * BB + b) * NPTS + n0 + w * 16 + lg * 4;
#pragma unroll
    for (int j = 0; j < 4; ++j) psum[base + j] = sf[j];
  }
}

__global__ __launch_bounds__(256) void combine_sum(
    const float* __restrict__ psum, float* __restrict__ rinv)
{
  const long i = (long)blockIdx.x * 256 + threadIdx.x;
  const long st = (long)BB * NPTS;
  rinv[i] = 1.f / ((psum[i] + psum[st + i]) + (psum[2 * st + i] + psum[3 * st + i]));
}

// ---------------------------------------------------------------------------
// pass2 (round-4/10/12 winner, verbatim): m-tile 64, grid 256, n-step 128,
// double-buffered P, one lgkm-only barrier/iter, XCD-swizzled.
// Epilogue: colsum renorm + off = x - nf written in place into XT.
__global__ __launch_bounds__(512) void pass2_mfma(
    const short* __restrict__ KT, const short* __restrict__ Vblk,
    const float* __restrict__ rmax, const float* __restrict__ rinv,
    short* __restrict__ XO)
{
  const int bid = blockIdx.x;
  const int b  = (bid >> 1) & 3;
  const int m0 = ((bid >> 3) * 2 + (bid & 1)) * 64;   // 0..4032
  const int tid = threadIdx.x;
  const int w = tid >> 6, l = tid & 63, lg = l >> 4, lr = l & 15;

  const short* Kb = KT + (long)b * NPTS * DQ;
  const short* Vb = Vblk + (long)b * CO * NPTS;
  const float* rmb = rmax + (long)b * NPTS;
  const float* rib = rinv + (long)b * NPTS;

  __shared__ short Ps[2][64][PST];
  __shared__ float cspart[8][64];
  __shared__ float csum[64];

  bf16x8 bK[4][2];
#pragma unroll
  for (int ms = 0; ms < 4; ++ms) {
    bK[ms][0] = *(const bf16x8*)&Kb[(long)(m0 + ms * 16 + lr) * DQ + lg * 8];
    bK[ms][1] = *(const bf16x8*)&Kb[(long)(m0 + ms * 16 + lr) * DQ + 32 + lg * 8];
  }

  f32x4 acc[4][2];
#pragma unroll
  for (int i = 0; i < 4; ++i) {
    acc[i][0] = (f32x4){0.f, 0.f, 0.f, 0.f};
    acc[i][1] = (f32x4){0.f, 0.f, 0.f, 0.f};
  }
  float cs[4] = {0.f, 0.f, 0.f, 0.f};
  const int c0 = w * 32;
  const int nb = w * 16;

  bf16x8 a0 = *(const bf16x8*)&Kb[(long)(nb + lr) * DQ + lg * 8];
  bf16x8 a1 = *(const bf16x8*)&Kb[(long)(nb + lr) * DQ + 32 + lg * 8];
  float4 rm4 = *(const float4*)&rmb[nb + lg * 4];
  float4 ri4 = *(const float4*)&rib[nb + lg * 4];

  int buf = 0;
  for (int n0 = 0; n0 < NPTS; n0 += 128) {
    const short* vt = Vb + (long)(n0 >> 7) * CO * 128;
    bf16x8 vf[4][2];
#pragma unroll
    for (int kc = 0; kc < 4; ++kc) {
      vf[kc][0] = *(const bf16x8*)&vt[(long)(c0 + lr) * 128 + kc * 32 + lg * 8];
      vf[kc][1] = *(const bf16x8*)&vt[(long)(c0 + 16 + lr) * 128 + kc * 32 + lg * 8];
    }
    f32x4 s[4];
#pragma unroll
    for (int ms = 0; ms < 4; ++ms) {
      s[ms] = (f32x4){0.f, 0.f, 0.f, 0.f};
      s[ms] = MFMA16(a0, bK[ms][0], s[ms]);
      s[ms] = MFMA16(a1, bK[ms][1], s[ms]);
    }
#pragma unroll
    for (int ms = 0; ms < 4; ++ms) {
      const float p0 = __expf(s[ms][0] - rm4.x) * ri4.x;
      const float p1 = __expf(s[ms][1] - rm4.y) * ri4.y;
      const float p2 = __expf(s[ms][2] - rm4.z) * ri4.z;
      const float p3 = __expf(s[ms][3] - rm4.w) * ri4.w;
      cs[ms] += p0 + p1 + p2 + p3;
      const unsigned u0 = ((unsigned)(unsigned short)fb(p1) << 16) | (unsigned short)fb(p0);
      const unsigned u1 = ((unsigned)(unsigned short)fb(p3) << 16) | (unsigned short)fb(p2);
      *(uint2*)&Ps[buf][ms * 16 + lr][nb + lg * 4] = make_uint2(u0, u1);
    }
    asm volatile("s_waitcnt lgkmcnt(0)" ::: "memory");
    __builtin_amdgcn_s_barrier();
    if (n0 + 128 < NPTS) {
      a0  = *(const bf16x8*)&Kb[(long)(n0 + 128 + nb + lr) * DQ + lg * 8];
      a1  = *(const bf16x8*)&Kb[(long)(n0 + 128 + nb + lr) * DQ + 32 + lg * 8];
      rm4 = *(const float4*)&rmb[n0 + 128 + nb + lg * 4];
      ri4 = *(const float4*)&rib[n0 + 128 + nb + lg * 4];
    }
#pragma unroll
    for (int kc = 0; kc < 4; ++kc) {
      bf16x8 pa[4];
#pragma unroll
      for (int ms = 0; ms < 4; ++ms)
        pa[ms] = *(const bf16x8*)&Ps[buf][ms * 16 + lr][kc * 32 + lg * 8];
#pragma unroll
      for (int ms = 0; ms < 4; ++ms) {
        acc[ms][0] = MFMA16(pa[ms], vf[kc][0], acc[ms][0]);
        acc[ms][1] = MFMA16(pa[ms], vf[kc][1], acc[ms][1]);
      }
    }
    buf ^= 1;
  }

  __syncthreads();
#pragma unroll
  for (int ms = 0; ms < 4; ++ms) {
    float csv = cs[ms];
    csv += __shfl_xor(csv, 16); csv += __shfl_xor(csv, 32);
    if (lg == 0) cspart[w][ms * 16 + lr] = csv;
  }
  __syncthreads();
  if (tid < 64) {
    float s = 0.f;
#pragma unroll
    for (int ww = 0; ww < 8; ++ww) s += cspart[ww][tid];
    csum[tid] = s;
  }
  __syncthreads();

  short* XOb = XO + (long)b * NPTS * CO;
#pragma unroll
  for (int ms = 0; ms < 4; ++ms) {
#pragma unroll
    for (int j = 0; j < 4; ++j) {
      const int m = m0 + ms * 16 + lg * 4 + j;
      const float inv = 1.f / (1e-9f + csum[ms * 16 + lg * 4 + j]);
      const long i0 = (long)m * CO + c0 + lr;
      const long i1 = (long)m * CO + c0 + 16 + lr;
      XOb[i0] = fb(bf(XOb[i0]) - acc[ms][0][j] * inv);
      XOb[i1] = fb(bf(XOb[i1]) - acc[ms][1][j] * inv);
    }
  }
}

// ---------------------------------------------------------------------------
extern "C" void kernel_launch(void* const* d_in, const int* in_sizes, int n_in,
                              void* d_out, int out_size, void* d_ws, size_t ws_size,
                              hipStream_t stream)
{
  const float* feat = (const float*)d_in[0];
  const float* w1   = (const float*)d_in[1];
  const float* g1   = (const float*)d_in[2];
  const float* b1   = (const float*)d_in[3];
  const float* w2   = (const float*)d_in[4];
  const float* g2   = (const float*)d_in[5];
  const float* b2   = (const float*)d_in[6];
  const float* qkw  = (const float*)d_in[7];
  const float* vw   = (const float*)d_in[8];
  const float* vb   = (const float*)d_in[9];
  const float* tw   = (const float*)d_in[10];
  const float* tb   = (const float*)d_in[11];
  const float* bng  = (const float*)d_in[12];
  const float* bnb  = (const float*)d_in[13];

  float* out = (float*)d_out;

  // workspace (~21 MB)
  short* xt    = (short*)d_ws;                        // [B][N][CO] bf16 (x^T / off^T)
  short* KTb   = xt + (long)BB * NPTS * CO;           // [B][N][DQ]
  short* Vblk  = KTb + (long)BB * NPTS * DQ;          // [B][N/128][CO][128]; aliased as
                                                      // bf16 pre-BN [B][CO][N] (h1/x0/t)
  short* wb1   = Vblk + (long)BB * CO * NPTS;         // CO*CI
  short* wb2   = wb1 + (long)CO * CI;                 // CO*CO
  short* wqk   = wb2 + (long)CO * CO;                 // L*DQ*CO
  short* wv    = wqk + (long)LL * DQ * CO;            // L*CO*CO
  short* wt    = wv + (long)LL * CO * CO;             // L*CO*CO
  float* psumb = (float*)(wt + (long)LL * CO * CO);   // [4][B][N]
  float* nrm2b = psumb + (long)4 * BB * NPTS;         // [B][N]
  float* rmaxb = nrm2b + (long)BB * NPTS;             // [B][N] (bound M)
  float* rinvb = rmaxb + (long)BB * NPTS;             // [B][N]
  float* ps1   = rinvb + (long)BB * NPTS;             // [CO][256] BN partial sum
  float* ps2   = ps1 + (long)CO * 256;                // [CO][256] BN partial sumsq

  const long OBS = (long)LL * CO * NPTS;   // d_out batch stride
  const long TBS = (long)CO * NPTS;        // bf16 pre-BN tensor batch stride
  short* pre = Vblk;                       // bf16 pre-BN tensor alias

  const dim3 blk(256);

  // ---- weight pre-convert (single launch) ----
  {
    const int n1 = CO * CI / 8, n2 = CO * CO / 8, n3 = LL * DQ * CO / 8,
              n4 = LL * CO * CO / 8, n5 = LL * CO * CO / 8;
    const int tot = n1 + n2 + n3 + n4 + n5;
    cvt5_k<<<dim3((tot + 255) / 256), blk, 0, stream>>>(
        w1, wb1, n1, w2, wb2, n2, qkw, wqk, n3, vw, wv, n4, tw, wt, n5);
  }

  // ---- stem ----
  tcvt_k<<<dim3(64, 2, BB), blk, 0, stream>>>(feat, (long)CI * NPTS, CI, xt);
  conv_a<2, false><<<dim3(64, 4, BB), blk, 0, stream>>>(
      xt, CI, wb1, nullptr, pre, TBS, ps1, ps2);
  bnrelu_t<false, true><<<dim3(64, 4, BB), blk, 0, stream>>>(
      pre, TBS, ps1, ps2, g1, b1, nullptr, 0, xt);
  conv_a<2, false><<<dim3(64, 4, BB), blk, 0, stream>>>(
      xt, CO, wb2, nullptr, pre, TBS, ps1, ps2);
  bnrelu_t<false, true><<<dim3(64, 4, BB), blk, 0, stream>>>(
      pre, TBS, ps1, ps2, g2, b2, nullptr, 0, xt);

  // ---- stacked offset attention ----
  for (int lyr = 0; lyr < LL; ++lyr) {
    float* nft = out + (long)lyr * CO * NPTS;
    conv_kv<<<dim3(BB * 64 + BB * 4 * 64), blk, 0, stream>>>(
        xt, wqk + (long)lyr * DQ * CO, KTb, nrm2b,
        wv + (long)lyr * CO * CO, vb + (long)lyr * CO, Vblk);
    rowsum_mfma<<<dim3(1024), blk, 0, stream>>>(KTb, nrm2b, rmaxb, psumb);
    combine_sum<<<dim3(BB * NPTS / 256), blk, 0, stream>>>(psumb, rinvb);
    pass2_mfma<<<dim3(256), dim3(512), 0, stream>>>(KTb, Vblk, rmaxb, rinvb, xt);
    // t = tw @ off + tb  (bf16 out + BN partials; Vblk is free again)
    conv_a<2, true><<<dim3(64, 4, BB), blk, 0, stream>>>(
        xt, CO, wt + (long)lyr * CO * CO, tb + (long)lyr * CO, pre, TBS, ps1, ps2);
    if (lyr < LL - 1) {
      bnrelu_t<true, true><<<dim3(64, 4, BB), blk, 0, stream>>>(
          pre, TBS, ps1, ps2, bng + (long)lyr * CO, bnb + (long)lyr * CO, nft, OBS, xt);
    } else {
      bnrelu_t<true, false><<<dim3(64, 4, BB), blk, 0, stream>>>(
          pre, TBS, ps1, ps2, bng + (long)lyr * CO, bnb + (long)lyr * CO, nft, OBS, nullptr);
    }
  }
}

// Round 14
// 905.873 us; speedup vs baseline: 1.0809x; 1.0809x over previous
//
#include <hip/hip_runtime.h>
#include <hip/hip_bf16.h>
#include <math.h>

#define NPTS 4096
#define CO   256
#define CI   128
#define BB   4
#define DQ   64
#define LL   4
#define PST  136   // Ps row stride in shorts (272B; 16B-aligned rows)

typedef __attribute__((ext_vector_type(8))) short bf16x8;
typedef __attribute__((ext_vector_type(4))) float f32x4;

#define MFMA16(a,b,c) __builtin_amdgcn_mfma_f32_16x16x32_bf16((a),(b),(c),0,0,0)

__device__ __forceinline__ short fb(float x) {
  __hip_bfloat16 h = __float2bfloat16(x);
  return __builtin_bit_cast(short, h);
}
__device__ __forceinline__ float bf(short s) {
  unsigned u = ((unsigned)(unsigned short)s) << 16;
  return __builtin_bit_cast(float, u);
}

// ---------------------------------------------------------------------------
// one-shot fp32 -> bf16 convert of all 5 weight tensors
__global__ __launch_bounds__(256) void cvt5_k(
    const float* __restrict__ s1, short* __restrict__ d1, int n1,
    const float* __restrict__ s2, short* __restrict__ d2, int n2,
    const float* __restrict__ s3, short* __restrict__ d3, int n3,
    const float* __restrict__ s4, short* __restrict__ d4, int n4,
    const float* __restrict__ s5, short* __restrict__ d5, int n5)
{
  int i = blockIdx.x * 256 + threadIdx.x;
  const float* S; short* D;
  if      (i < n1)                       { S = s1; D = d1; }
  else if ((i -= n1) < n2)               { S = s2; D = d2; }
  else if ((i -= n2) < n3)               { S = s3; D = d3; }
  else if ((i -= n3) < n4)               { S = s4; D = d4; }
  else if ((i -= n4) < n5)               { S = s5; D = d5; }
  else return;
  const float4 a = ((const float4*)S)[i * 2];
  const float4 b = ((const float4*)S)[i * 2 + 1];
  bf16x8 r;
  r[0] = fb(a.x); r[1] = fb(a.y); r[2] = fb(a.z); r[3] = fb(a.w);
  r[4] = fb(b.x); r[5] = fb(b.y); r[6] = fb(b.z); r[7] = fb(b.w);
  ((bf16x8*)D)[i] = r;
}

// ---------------------------------------------------------------------------
// fp32 [b][C][N] -> bf16 [b][N][C] transpose-convert (stem input only)
__global__ __launch_bounds__(256) void tcvt_k(
    const float* __restrict__ X, long xbs, int C, short* __restrict__ XT)
{
  const int n0 = blockIdx.x * 64, c0 = blockIdx.y * 64, b = blockIdx.z;
  const int t = threadIdx.x, tl = t & 63, tg = t >> 6;
  __shared__ float xs[64][65];
#pragma unroll
  for (int r = 0; r < 16; ++r) {
    const int cc = tg * 16 + r;
    xs[cc][tl] = X[(long)b * xbs + (long)(c0 + cc) * NPTS + n0 + tl];
  }
  __syncthreads();
#pragma unroll
  for (int r = 0; r < 16; ++r) {
    const int nn = tg * 16 + r;
    XT[((long)b * NPTS + n0 + nn) * C + c0 + tl] = fb(xs[tl][nn]);
  }
}

// ---------------------------------------------------------------------------
// conv_a: Y[b][d][n] = sum_c Wb[d][c] * XT[b][n][c] (+bias), bf16 weights.
// OMODE 2: bf16 [d][N] + per-(channel, b, n-block) BN partial stats
template<int OMODE, bool BIAS>
__global__ __launch_bounds__(256) void conv_a(
    const short* __restrict__ XT, int C,
    const short* __restrict__ Wb, const float* __restrict__ bias,
    short* __restrict__ Yv, long ybs,
    float* __restrict__ ps1, float* __restrict__ ps2)
{
  const int n0 = blockIdx.x * 64, d0 = blockIdx.y * 64, b = blockIdx.z;
  const int tid = threadIdx.x, w = tid >> 6, l = tid & 63, lg = l >> 4, lr = l & 15;
  const short* xb = XT + (long)b * NPTS * C;
  f32x4 acc[4];
#pragma unroll
  for (int i = 0; i < 4; ++i) acc[i] = (f32x4){0.f, 0.f, 0.f, 0.f};
  const int dr = d0 + w * 16 + lr;
  for (int kc = 0; kc < C; kc += 32) {
    const bf16x8 af = *(const bf16x8*)&Wb[(long)dr * C + kc + lg * 8];
#pragma unroll
    for (int ni = 0; ni < 4; ++ni) {
      const bf16x8 bx = *(const bf16x8*)&xb[(long)(n0 + ni * 16 + lr) * C + kc + lg * 8];
      acc[ni] = MFMA16(af, bx, acc[ni]);
    }
  }
  float bv[4] = {0.f, 0.f, 0.f, 0.f};
  if (BIAS) {
    const float4 b4 = *(const float4*)&bias[d0 + w * 16 + lg * 4];
    bv[0] = b4.x; bv[1] = b4.y; bv[2] = b4.z; bv[3] = b4.w;
  }
  const int db = d0 + w * 16 + lg * 4;
  float s1[4], s2[4];
#pragma unroll
  for (int j = 0; j < 4; ++j) { s1[j] = 0.f; s2[j] = 0.f; }
#pragma unroll
  for (int ni = 0; ni < 4; ++ni) {
    const int n = n0 + ni * 16 + lr;
#pragma unroll
    for (int j = 0; j < 4; ++j) {
      const short ob = fb(acc[ni][j] + bv[j]);
      if constexpr (OMODE == 1) {
        Yv[(long)b * ybs + ((long)(n >> 7) * CO + db + j) * 128 + (n & 127)] = ob;
      } else {
        Yv[(long)b * ybs + (long)(db + j) * NPTS + n] = ob;
        const float o = bf(ob);   // stats on rounded value (self-consistent BN)
        s1[j] += o; s2[j] += o * o;
      }
    }
  }
  if constexpr (OMODE == 2) {
#pragma unroll
    for (int j = 0; j < 4; ++j) {
#pragma unroll
      for (int off = 1; off < 16; off <<= 1) {
        s1[j] += __shfl_xor(s1[j], off);
        s2[j] += __shfl_xor(s2[j], off);
      }
    }
    if (lr == 0) {
      const int slot = b * 64 + blockIdx.x;   // 256 slots per channel
#pragma unroll
      for (int j = 0; j < 4; ++j) {
        ps1[(long)(db + j) * 256 + slot] = s1[j];
        ps2[(long)(db + j) * 256 + slot] = s2[j];
      }
    }
  }
}

// ---------------------------------------------------------------------------
// conv_kv: fused K-projection (with row norms) + V-projection.
// blocks [0, 256): K role — KT[b][n][d] = XT@Wk^T, nrm2[b][n] = ||K_n||^2
// blocks [256, 1280): V role — Vblk n-blocked [n>>7][d][128] = XT@Wv^T + vb
__global__ __launch_bounds__(256) void conv_kv(
    const short* __restrict__ XT,
    const short* __restrict__ Wk, short* __restrict__ KTo, float* __restrict__ nrm2,
    const short* __restrict__ Wv, const float* __restrict__ vbias,
    short* __restrict__ Vblk)
{
  const int tid = threadIdx.x, w = tid >> 6, l = tid & 63, lg = l >> 4, lr = l & 15;
  const int bid = blockIdx.x;
  if (bid < BB * 64) {
    // ---- K role ----
    const int n0 = (bid & 63) * 64, b = bid >> 6;
    const short* xb = XT + (long)b * NPTS * CO;
    f32x4 acc[4];
#pragma unroll
    for (int i = 0; i < 4; ++i) acc[i] = (f32x4){0.f, 0.f, 0.f, 0.f};
    const long nr = n0 + w * 16 + lr;
    for (int kc = 0; kc < CO; kc += 32) {
      const bf16x8 af = *(const bf16x8*)&xb[nr * CO + kc + lg * 8];
#pragma unroll
      for (int di = 0; di < 4; ++di) {
        const bf16x8 wf = *(const bf16x8*)&Wk[(long)(di * 16 + lr) * CO + kc + lg * 8];
        acc[di] = MFMA16(af, wf, acc[di]);
      }
    }
    short* Ko = KTo + (long)b * NPTS * DQ;
    const int nb = n0 + w * 16 + lg * 4;
    float nv[4];
#pragma unroll
    for (int j = 0; j < 4; ++j) {
      nv[j] = 0.f;
#pragma unroll
      for (int di = 0; di < 4; ++di) {
        Ko[(long)(nb + j) * DQ + di * 16 + lr] = fb(acc[di][j]);
        nv[j] = fmaf(acc[di][j], acc[di][j], nv[j]);
      }
    }
#pragma unroll
    for (int j = 0; j < 4; ++j) {
#pragma unroll
      for (int off = 1; off < 16; off <<= 1) nv[j] += __shfl_xor(nv[j], off);
    }
    if (lr == 0) {
#pragma unroll
      for (int j = 0; j < 4; ++j) nrm2[(long)b * NPTS + nb + j] = nv[j];
    }
  } else {
    // ---- V role ----
    const int id = bid - BB * 64;
    const int n0 = (id & 63) * 64, d0 = ((id >> 6) & 3) * 64, b = id >> 8;
    const short* xb = XT + (long)b * NPTS * CO;
    f32x4 acc[4];
#pragma unroll
    for (int i = 0; i < 4; ++i) acc[i] = (f32x4){0.f, 0.f, 0.f, 0.f};
    const int dr = d0 + w * 16 + lr;
    for (int kc = 0; kc < CO; kc += 32) {
      const bf16x8 af = *(const bf16x8*)&Wv[(long)dr * CO + kc + lg * 8];
#pragma unroll
      for (int ni = 0; ni < 4; ++ni) {
        const bf16x8 bx = *(const bf16x8*)&xb[(long)(n0 + ni * 16 + lr) * CO + kc + lg * 8];
        acc[ni] = MFMA16(af, bx, acc[ni]);
      }
    }
    const float4 b4 = *(const float4*)&vbias[d0 + w * 16 + lg * 4];
    const float bv[4] = {b4.x, b4.y, b4.z, b4.w};
    const int db = d0 + w * 16 + lg * 4;
#pragma unroll
    for (int ni = 0; ni < 4; ++ni) {
      const int n = n0 + ni * 16 + lr;
#pragma unroll
      for (int j = 0; j < 4; ++j)
        Vblk[(long)b * CO * NPTS + ((long)(n >> 7) * CO + db + j) * 128 + (n & 127)] =
            fb(acc[ni][j] + bv[j]);
    }
  }
}

// ---------------------------------------------------------------------------
// bound_k: per batch, maxnrm2 = max_n nrm2; M_n = sqrt(nrm2[n] * maxnrm2).
// Cauchy-Schwarz upper bound on row max of S; softmax is shift-invariant.
__global__ __launch_bounds__(256) void bound_k(
    const float* __restrict__ nrm2, float* __restrict__ rmax)
{
  const int b = blockIdx.x, t = threadIdx.x;
  __shared__ float red[4];
  float mx = 0.f;
  for (int n = t; n < NPTS; n += 256) mx = fmaxf(mx, nrm2[(long)b * NPTS + n]);
#pragma unroll
  for (int o = 32; o > 0; o >>= 1) mx = fmaxf(mx, __shfl_down(mx, o));
  if ((t & 63) == 0) red[t >> 6] = mx;
  __syncthreads();
  const float mv = fmaxf(fmaxf(red[0], red[1]), fmaxf(red[2], red[3]));
  for (int n = t; n < NPTS; n += 256)
    rmax[(long)b * NPTS + n] = sqrtf(nrm2[(long)b * NPTS + n] * mv);
}

// ---------------------------------------------------------------------------
// BN finalize from partials: mean/rstd per channel
__global__ __launch_bounds__(64) void bnfin_k(
    const float* __restrict__ ps1, const float* __restrict__ ps2,
    float* __restrict__ mean, float* __restrict__ rstd)
{
  const int c = blockIdx.x, t = threadIdx.x;
  float s = 0.f, s2 = 0.f;
#pragma unroll
  for (int i = 0; i < 4; ++i) {
    s  += ps1[(long)c * 256 + t + i * 64];
    s2 += ps2[(long)c * 256 + t + i * 64];
  }
#pragma unroll
  for (int o = 32; o > 0; o >>= 1) { s += __shfl_down(s, o); s2 += __shfl_down(s2, o); }
  if (t == 0) {
    const float m = s / (float)(BB * NPTS);
    const float v = s2 / (float)(BB * NPTS) - m * m;
    mean[c] = m;
    rstd[c] = rsqrtf(v + 1e-5f);
  }
}

// ---------------------------------------------------------------------------
// BN normalize + affine + ReLU on bf16 pre-BN tensor [b][c][N];
// optionally write fp32 [c][n] (final out) and/or bf16 transpose [n][CO]
template<bool WF32, bool WBF>
__global__ __launch_bounds__(256) void bnrelu_t(
    const short* __restrict__ X, long xbs,
    const float* __restrict__ mean, const float* __restrict__ rstd,
    const float* __restrict__ g, const float* __restrict__ be,
    float* __restrict__ Yf, long ybs, short* __restrict__ XT)
{
  const int n0 = blockIdx.x * 64, c0 = blockIdx.y * 64, b = blockIdx.z;
  const int t = threadIdx.x, tl = t & 63, tg = t >> 6;
  __shared__ float xs[64][65];
#pragma unroll
  for (int r = 0; r < 16; ++r) {
    const int cc = tg * 16 + r, c = c0 + cc;
    float v = bf(X[(long)b * xbs + (long)c * NPTS + n0 + tl]);
    v = fmaxf((v - mean[c]) * rstd[c] * g[c] + be[c], 0.f);
    if (WF32) Yf[(long)b * ybs + (long)c * NPTS + n0 + tl] = v;
    xs[cc][tl] = v;
  }
  __syncthreads();
  if (WBF) {
#pragma unroll
    for (int r = 0; r < 16; ++r) {
      const int nn = tg * 16 + r;
      XT[((long)b * NPTS + n0 + nn) * CO + c0 + tl] = fb(xs[tl][nn]);
    }
  }
}

// ---------------------------------------------------------------------------
// rowsum: psum[chunk][b][n] = sum_{m in chunk} exp(S[n,m] - M_n).
// Pure-sum pass (no online max): M from bound_k. XCD-swizzled flat grid.
__global__ __launch_bounds__(256) void rowsum_mfma(
    const short* __restrict__ KT, const float* __restrict__ rmax,
    float* __restrict__ psum)
{
  const int bid = blockIdx.x;
  const int b = (bid >> 1) & 3;
  const int idx = (bid >> 3) * 2 + (bid & 1);   // 0..255
  const int n0 = (idx & 63) * 64;
  const int chunk = idx >> 6;
  const int tid = threadIdx.x, w = tid >> 6, l = tid & 63, lg = l >> 4, lr = l & 15;
  const short* Kb = KT + (long)b * NPTS * DQ;
  const int nr = n0 + w * 16 + lr;
  const bf16x8 a0 = *(const bf16x8*)&Kb[(long)nr * DQ + lg * 8];
  const bf16x8 a1 = *(const bf16x8*)&Kb[(long)nr * DQ + 32 + lg * 8];
  const float4 M4 = *(const float4*)&rmax[(long)b * NPTS + n0 + w * 16 + lg * 4];

  float sm[4][4];
#pragma unroll
  for (int p = 0; p < 4; ++p)
#pragma unroll
    for (int j = 0; j < 4; ++j) sm[p][j] = 0.f;

  const int mc = chunk * (NPTS / 4);
  for (int m0 = mc; m0 < mc + NPTS / 4; m0 += 64) {
#pragma unroll
    for (int p = 0; p < 4; ++p) {
      const bf16x8 b0 = *(const bf16x8*)&Kb[(long)(m0 + p * 16 + lr) * DQ + lg * 8];
      const bf16x8 b1 = *(const bf16x8*)&Kb[(long)(m0 + p * 16 + lr) * DQ + 32 + lg * 8];
      f32x4 s = {0.f, 0.f, 0.f, 0.f};
      s = MFMA16(a0, b0, s);
      s = MFMA16(a1, b1, s);
      sm[p][0] += __expf(s[0] - M4.x);
      sm[p][1] += __expf(s[1] - M4.y);
      sm[p][2] += __expf(s[2] - M4.z);
      sm[p][3] += __expf(s[3] - M4.w);
    }
  }
  float sf[4];
#pragma unroll
  for (int j = 0; j < 4; ++j)
    sf[j] = (sm[0][j] + sm[1][j]) + (sm[2][j] + sm[3][j]);
#pragma unroll
  for (int off = 1; off < 16; off <<= 1)
#pragma unroll
    for (int j = 0; j < 4; ++j) sf[j] += __shfl_xor(sf[j], off);

  if (lr == 0) {
    const long base = ((long)chunk * BB + b) * NPTS + n0 + w * 16 + lg * 4;
#pragma unroll
    for (int j = 0; j < 4; ++j) psum[base + j] = sf[j];
  }
}

__global__ __launch_bounds__(256) void combine_sum(
    const float* __restrict__ psum, float* __restrict__ rinv)
{
  const long i = (long)blockIdx.x * 256 + threadIdx.x;
  const long st = (long)BB * NPTS;
  rinv[i] = 1.f / ((psum[i] + psum[st + i]) + (psum[2 * st + i] + psum[3 * st + i]));
}

// ---------------------------------------------------------------------------
// pass2 (round-4/10/12 winner, verbatim): m-tile 64, grid 256, n-step 128,
// double-buffered P, one lgkm-only barrier/iter, XCD-swizzled.
// Epilogue: colsum renorm + off = x - nf written in place into XT.
__global__ __launch_bounds__(512) void pass2_mfma(
    const short* __restrict__ KT, const short* __restrict__ Vblk,
    const float* __restrict__ rmax, const float* __restrict__ rinv,
    short* __restrict__ XO)
{
  const int bid = blockIdx.x;
  const int b  = (bid >> 1) & 3;
  const int m0 = ((bid >> 3) * 2 + (bid & 1)) * 64;   // 0..4032
  const int tid = threadIdx.x;
  const int w = tid >> 6, l = tid & 63, lg = l >> 4, lr = l & 15;

  const short* Kb = KT + (long)b * NPTS * DQ;
  const short* Vb = Vblk + (long)b * CO * NPTS;
  const float* rmb = rmax + (long)b * NPTS;
  const float* rib = rinv + (long)b * NPTS;

  __shared__ short Ps[2][64][PST];
  __shared__ float cspart[8][64];
  __shared__ float csum[64];

  bf16x8 bK[4][2];
#pragma unroll
  for (int ms = 0; ms < 4; ++ms) {
    bK[ms][0] = *(const bf16x8*)&Kb[(long)(m0 + ms * 16 + lr) * DQ + lg * 8];
    bK[ms][1] = *(const bf16x8*)&Kb[(long)(m0 + ms * 16 + lr) * DQ + 32 + lg * 8];
  }

  f32x4 acc[4][2];
#pragma unroll
  for (int i = 0; i < 4; ++i) {
    acc[i][0] = (f32x4){0.f, 0.f, 0.f, 0.f};
    acc[i][1] = (f32x4){0.f, 0.f, 0.f, 0.f};
  }
  float cs[4] = {0.f, 0.f, 0.f, 0.f};
  const int c0 = w * 32;
  const int nb = w * 16;

  bf16x8 a0 = *(const bf16x8*)&Kb[(long)(nb + lr) * DQ + lg * 8];
  bf16x8 a1 = *(const bf16x8*)&Kb[(long)(nb + lr) * DQ + 32 + lg * 8];
  float4 rm4 = *(const float4*)&rmb[nb + lg * 4];
  float4 ri4 = *(const float4*)&rib[nb + lg * 4];

  int buf = 0;
  for (int n0 = 0; n0 < NPTS; n0 += 128) {
    const short* vt = Vb + (long)(n0 >> 7) * CO * 128;
    bf16x8 vf[4][2];
#pragma unroll
    for (int kc = 0; kc < 4; ++kc) {
      vf[kc][0] = *(const bf16x8*)&vt[(long)(c0 + lr) * 128 + kc * 32 + lg * 8];
      vf[kc][1] = *(const bf16x8*)&vt[(long)(c0 + 16 + lr) * 128 + kc * 32 + lg * 8];
    }
    f32x4 s[4];
#pragma unroll
    for (int ms = 0; ms < 4; ++ms) {
      s[ms] = (f32x4){0.f, 0.f, 0.f, 0.f};
      s[ms] = MFMA16(a0, bK[ms][0], s[ms]);
      s[ms] = MFMA16(a1, bK[ms][1], s[ms]);
    }
#pragma unroll
    for (int ms = 0; ms < 4; ++ms) {
      const float p0 = __expf(s[ms][0] - rm4.x) * ri4.x;
      const float p1 = __expf(s[ms][1] - rm4.y) * ri4.y;
      const float p2 = __expf(s[ms][2] - rm4.z) * ri4.z;
      const float p3 = __expf(s[ms][3] - rm4.w) * ri4.w;
      cs[ms] += p0 + p1 + p2 + p3;
      const unsigned u0 = ((unsigned)(unsigned short)fb(p1) << 16) | (unsigned short)fb(p0);
      const unsigned u1 = ((unsigned)(unsigned short)fb(p3) << 16) | (unsigned short)fb(p2);
      *(uint2*)&Ps[buf][ms * 16 + lr][nb + lg * 4] = make_uint2(u0, u1);
    }
    asm volatile("s_waitcnt lgkmcnt(0)" ::: "memory");
    __builtin_amdgcn_s_barrier();
    if (n0 + 128 < NPTS) {
      a0  = *(const bf16x8*)&Kb[(long)(n0 + 128 + nb + lr) * DQ + lg * 8];
      a1  = *(const bf16x8*)&Kb[(long)(n0 + 128 + nb + lr) * DQ + 32 + lg * 8];
      rm4 = *(const float4*)&rmb[n0 + 128 + nb + lg * 4];
      ri4 = *(const float4*)&rib[n0 + 128 + nb + lg * 4];
    }
#pragma unroll
    for (int kc = 0; kc < 4; ++kc) {
      bf16x8 pa[4];
#pragma unroll
      for (int ms = 0; ms < 4; ++ms)
        pa[ms] = *(const bf16x8*)&Ps[buf][ms * 16 + lr][kc * 32 + lg * 8];
#pragma unroll
      for (int ms = 0; ms < 4; ++ms) {
        acc[ms][0] = MFMA16(pa[ms], vf[kc][0], acc[ms][0]);
        acc[ms][1] = MFMA16(pa[ms], vf[kc][1], acc[ms][1]);
      }
    }
    buf ^= 1;
  }

  __syncthreads();
#pragma unroll
  for (int ms = 0; ms < 4; ++ms) {
    float csv = cs[ms];
    csv += __shfl_xor(csv, 16); csv += __shfl_xor(csv, 32);
    if (lg == 0) cspart[w][ms * 16 + lr] = csv;
  }
  __syncthreads();
  if (tid < 64) {
    float s = 0.f;
#pragma unroll
    for (int ww = 0; ww < 8; ++ww) s += cspart[ww][tid];
    csum[tid] = s;
  }
  __syncthreads();

  short* XOb = XO + (long)b * NPTS * CO;
#pragma unroll
  for (int ms = 0; ms < 4; ++ms) {
#pragma unroll
    for (int j = 0; j < 4; ++j) {
      const int m = m0 + ms * 16 + lg * 4 + j;
      const float inv = 1.f / (1e-9f + csum[ms * 16 + lg * 4 + j]);
      const long i0 = (long)m * CO + c0 + lr;
      const long i1 = (long)m * CO + c0 + 16 + lr;
      XOb[i0] = fb(bf(XOb[i0]) - acc[ms][0][j] * inv);
      XOb[i1] = fb(bf(XOb[i1]) - acc[ms][1][j] * inv);
    }
  }
}

// ---------------------------------------------------------------------------
extern "C" void kernel_launch(void* const* d_in, const int* in_sizes, int n_in,
                              void* d_out, int out_size, void* d_ws, size_t ws_size,
                              hipStream_t stream)
{
  const float* feat = (const float*)d_in[0];
  const float* w1   = (const float*)d_in[1];
  const float* g1   = (const float*)d_in[2];
  const float* b1   = (const float*)d_in[3];
  const float* w2   = (const float*)d_in[4];
  const float* g2   = (const float*)d_in[5];
  const float* b2   = (const float*)d_in[6];
  const float* qkw  = (const float*)d_in[7];
  const float* vw   = (const float*)d_in[8];
  const float* vb   = (const float*)d_in[9];
  const float* tw   = (const float*)d_in[10];
  const float* tb   = (const float*)d_in[11];
  const float* bng  = (const float*)d_in[12];
  const float* bnb  = (const float*)d_in[13];

  float* out = (float*)d_out;

  // workspace (~21 MB)
  short* xt    = (short*)d_ws;                        // [B][N][CO] bf16 (x^T / off^T)
  short* KTb   = xt + (long)BB * NPTS * CO;           // [B][N][DQ]
  short* Vblk  = KTb + (long)BB * NPTS * DQ;          // [B][N/128][CO][128]; aliased as
                                                      // bf16 pre-BN [B][CO][N] (h1/x0/t)
  short* wb1   = Vblk + (long)BB * CO * NPTS;         // CO*CI
  short* wb2   = wb1 + (long)CO * CI;                 // CO*CO
  short* wqk   = wb2 + (long)CO * CO;                 // L*DQ*CO
  short* wv    = wqk + (long)LL * DQ * CO;            // L*CO*CO
  short* wt    = wv + (long)LL * CO * CO;             // L*CO*CO
  float* psumb = (float*)(wt + (long)LL * CO * CO);   // [4][B][N]
  float* nrm2b = psumb + (long)4 * BB * NPTS;         // [B][N]
  float* rmaxb = nrm2b + (long)BB * NPTS;             // [B][N] (bound M)
  float* rinvb = rmaxb + (long)BB * NPTS;             // [B][N]
  float* ps1   = rinvb + (long)BB * NPTS;             // [CO][256] BN partial sum
  float* ps2   = ps1 + (long)CO * 256;                // [CO][256] BN partial sumsq
  float* meanb = ps2 + (long)CO * 256;                // [CO]
  float* rstdb = meanb + CO;

  const long OBS = (long)LL * CO * NPTS;   // d_out batch stride
  const long TBS = (long)CO * NPTS;        // bf16 pre-BN tensor batch stride
  short* pre = Vblk;                       // bf16 pre-BN tensor alias

  const dim3 blk(256);

  // ---- weight pre-convert (single launch) ----
  {
    const int n1 = CO * CI / 8, n2 = CO * CO / 8, n3 = LL * DQ * CO / 8,
              n4 = LL * CO * CO / 8, n5 = LL * CO * CO / 8;
    const int tot = n1 + n2 + n3 + n4 + n5;
    cvt5_k<<<dim3((tot + 255) / 256), blk, 0, stream>>>(
        w1, wb1, n1, w2, wb2, n2, qkw, wqk, n3, vw, wv, n4, tw, wt, n5);
  }

  // ---- stem ----
  tcvt_k<<<dim3(64, 2, BB), blk, 0, stream>>>(feat, (long)CI * NPTS, CI, xt);
  conv_a<2, false><<<dim3(64, 4, BB), blk, 0, stream>>>(
      xt, CI, wb1, nullptr, pre, TBS, ps1, ps2);
  bnfin_k<<<dim3(CO), dim3(64), 0, stream>>>(ps1, ps2, meanb, rstdb);
  bnrelu_t<false, true><<<dim3(64, 4, BB), blk, 0, stream>>>(
      pre, TBS, meanb, rstdb, g1, b1, nullptr, 0, xt);
  conv_a<2, false><<<dim3(64, 4, BB), blk, 0, stream>>>(
      xt, CO, wb2, nullptr, pre, TBS, ps1, ps2);
  bnfin_k<<<dim3(CO), dim3(64), 0, stream>>>(ps1, ps2, meanb, rstdb);
  bnrelu_t<false, true><<<dim3(64, 4, BB), blk, 0, stream>>>(
      pre, TBS, meanb, rstdb, g2, b2, nullptr, 0, xt);

  // ---- stacked offset attention ----
  for (int lyr = 0; lyr < LL; ++lyr) {
    float* nft = out + (long)lyr * CO * NPTS;
    conv_kv<<<dim3(BB * 64 + BB * 4 * 64), blk, 0, stream>>>(
        xt, wqk + (long)lyr * DQ * CO, KTb, nrm2b,
        wv + (long)lyr * CO * CO, vb + (long)lyr * CO, Vblk);
    bound_k<<<dim3(BB), blk, 0, stream>>>(nrm2b, rmaxb);
    rowsum_mfma<<<dim3(1024), blk, 0, stream>>>(KTb, rmaxb, psumb);
    combine_sum<<<dim3(BB * NPTS / 256), blk, 0, stream>>>(psumb, rinvb);
    pass2_mfma<<<dim3(256), dim3(512), 0, stream>>>(KTb, Vblk, rmaxb, rinvb, xt);
    // t = tw @ off + tb  (bf16 out + BN partials; Vblk is free again)
    conv_a<2, true><<<dim3(64, 4, BB), blk, 0, stream>>>(
        xt, CO, wt + (long)lyr * CO * CO, tb + (long)lyr * CO, pre, TBS, ps1, ps2);
    bnfin_k<<<dim3(CO), dim3(64), 0, stream>>>(ps1, ps2, meanb, rstdb);
    if (lyr < LL - 1) {
      bnrelu_t<true, true><<<dim3(64, 4, BB), blk, 0, stream>>>(
          pre, TBS, meanb, rstdb, bng + (long)lyr * CO, bnb + (long)lyr * CO, nft, OBS, xt);
    } else {
      bnrelu_t<true, false><<<dim3(64, 4, BB), blk, 0, stream>>>(
          pre, TBS, meanb, rstdb, bng + (long)lyr * CO, bnb + (long)lyr * CO, nft, OBS, nullptr);
    }
  }
}